// Round 6
// baseline (728.054 us; speedup 1.0000x reference)
//
#include <hip/hip_runtime.h>
#include <hip/hip_bf16.h>
#include <math.h>

// Problem constants
#define S_LEN 2048
#define HIDDEN 4096
#define N_HEADS 32
#define N_KV 8
#define HEAD_DIM 128

typedef __attribute__((ext_vector_type(8))) short short8;   // 8 bf16 = 4 VGPRs
typedef __attribute__((ext_vector_type(4))) float f32x4;    // MFMA C/D frag

typedef __attribute__((address_space(3))) unsigned int as3_u32;
typedef const __attribute__((address_space(1))) unsigned int as1_u32;

__device__ __forceinline__ void gload16(const void* g, void* lds) {
  __builtin_amdgcn_global_load_lds((as1_u32*)g, (as3_u32*)lds, 16, 0, 0);
}

__device__ __forceinline__ unsigned short f2bf(float f) {
  unsigned int u = __float_as_uint(f);
  return (unsigned short)((u + 0x7fff + ((u >> 16) & 1)) >> 16);  // RNE
}
__device__ __forceinline__ float bf2f(unsigned short u) {
  return __uint_as_float(((unsigned int)u) << 16);
}

// ---------------------------------------------------------------------------
// fp32 -> bf16 conversion, 4 elems/thread
// ---------------------------------------------------------------------------
__global__ void conv_bf16(const float* __restrict__ in, unsigned short* __restrict__ out, int n) {
  int i = (blockIdx.x * blockDim.x + threadIdx.x) * 4;
  if (i >= n) return;
  float4 v = *(const float4*)&in[i];
  ushort4 o;
  o.x = f2bf(v.x); o.y = f2bf(v.y); o.z = f2bf(v.z); o.w = f2bf(v.w);
  *(ushort4*)&out[i] = o;
}

// ---------------------------------------------------------------------------
// m97-style bf16 MFMA GEMM core: one 128x128 C-tile per 256-thread block.
// ---------------------------------------------------------------------------
__device__ __forceinline__ void storeC(float* C, float v) { *C = v; }
__device__ __forceinline__ void storeC(unsigned short* C, float v) { *C = f2bf(v); }

template <typename OutT>
__device__ __forceinline__ void gemm_core_128(
    const unsigned short* __restrict__ A, const unsigned short* __restrict__ B,
    OutT* __restrict__ C, int K, int ldc) {
  __shared__ unsigned short As[128 * 32];
  __shared__ unsigned short Bs[128 * 32];

  const int tid = threadIdx.x;
  const int w = tid >> 6;
  const int lane = tid & 63;
  const int wr = (w >> 1) * 64;
  const int wc = (w & 1) * 64;
  const int lrow = lane & 15;
  const int lk8 = lane >> 4;

  f32x4 acc[4][4];
#pragma unroll
  for (int i = 0; i < 4; i++)
#pragma unroll
    for (int j = 0; j < 4; j++) acc[i][j] = (f32x4){0.f, 0.f, 0.f, 0.f};

  const int sr = (lane >> 2);
  const int sc = (lane & 3) * 8;

  for (int k0 = 0; k0 < K; k0 += 32) {
    __syncthreads();
#pragma unroll
    for (int s = 0; s < 2; s++) {
      int r = w * 32 + s * 16 + sr;
      gload16(&A[(size_t)r * K + k0 + sc], &As[(w * 32 + s * 16) * 32]);
      gload16(&B[(size_t)r * K + k0 + sc], &Bs[(w * 32 + s * 16) * 32]);
    }
    __syncthreads();

    short8 a[4], b[4];
#pragma unroll
    for (int i = 0; i < 4; i++)
      a[i] = *(const short8*)&As[(wr + i * 16 + lrow) * 32 + lk8 * 8];
#pragma unroll
    for (int j = 0; j < 4; j++)
      b[j] = *(const short8*)&Bs[(wc + j * 16 + lrow) * 32 + lk8 * 8];
#pragma unroll
    for (int i = 0; i < 4; i++)
#pragma unroll
      for (int j = 0; j < 4; j++)
        acc[i][j] = __builtin_amdgcn_mfma_f32_16x16x32_bf16(a[i], b[j], acc[i][j], 0, 0, 0);
  }

#pragma unroll
  for (int i = 0; i < 4; i++)
#pragma unroll
    for (int j = 0; j < 4; j++) {
      int col = wc + j * 16 + lrow;
#pragma unroll
      for (int r = 0; r < 4; r++) {
        int row = wr + i * 16 + lk8 * 4 + r;
        storeC(&C[(size_t)row * ldc + col], acc[i][j][r]);
      }
    }
}

// Fused QKV projection -> bf16 outputs Qb [S,4096], Kb [S,1024], Vb [S,1024]
__global__ __launch_bounds__(256) void gemm_qkv(
    const unsigned short* __restrict__ Xb,
    const unsigned short* __restrict__ Wqb, const unsigned short* __restrict__ Wkb,
    const unsigned short* __restrict__ Wvb,
    unsigned short* __restrict__ Qb, unsigned short* __restrict__ Kb,
    unsigned short* __restrict__ Vb) {
  const int colBase = blockIdx.x * 128;
  const int rowBase = blockIdx.y * 128;
  const unsigned short* B;
  unsigned short* C;
  int ldc, ccol;
  if (colBase < 4096)      { B = Wqb + (size_t)colBase * HIDDEN;          C = Qb; ldc = 4096; ccol = colBase; }
  else if (colBase < 5120) { B = Wkb + (size_t)(colBase - 4096) * HIDDEN; C = Kb; ldc = 1024; ccol = colBase - 4096; }
  else                     { B = Wvb + (size_t)(colBase - 5120) * HIDDEN; C = Vb; ldc = 1024; ccol = colBase - 5120; }
  gemm_core_128(Xb + (size_t)rowBase * HIDDEN, B,
                C + (size_t)rowBase * ldc + ccol, HIDDEN, ldc);
}

// Output projection: [2048,4096](bf16) @ Wo^T -> fp32 out
__global__ __launch_bounds__(256) void gemm_out(
    const unsigned short* __restrict__ Ob, const unsigned short* __restrict__ Wob,
    float* __restrict__ C) {
  const int colBase = blockIdx.x * 128;
  const int rowBase = blockIdx.y * 128;
  gemm_core_128(Ob + (size_t)rowBase * HIDDEN, Wob + (size_t)colBase * HIDDEN,
                C + (size_t)rowBase * HIDDEN + colBase, HIDDEN, HIDDEN);
}

// ---------------------------------------------------------------------------
// RoPE in-place on bf16 Q [S,32,128] and K [S,8,128].
// Q additionally scaled by 1/sqrt(128) * log2(e)  (exp2-domain softmax).
// ---------------------------------------------------------------------------
#define QSCALE 0.12753102123752056f  // 0.08838834764831845 * 1.4426950408889634

__global__ void rope_kernel(unsigned short* __restrict__ Q, unsigned short* __restrict__ K) {
  int idx = blockIdx.x * blockDim.x + threadIdx.x;
  int d = idx & 63;
  int sh = idx >> 6;
  int h = sh % (N_HEADS + N_KV);
  int s = sh / (N_HEADS + N_KV);
  if (s >= S_LEN) return;

  float freq = expf(-(float)d * (9.210340371976184f / 64.0f));
  float ang = (float)s * freq;
  float sn, cs;
  sincosf(ang, &sn, &cs);

  unsigned short* ptr;
  float sc_out;
  if (h < N_HEADS) {
    ptr = Q + ((size_t)s * N_HEADS + h) * HEAD_DIM;
    sc_out = QSCALE;
  } else {
    ptr = K + ((size_t)s * N_KV + (h - N_HEADS)) * HEAD_DIM;
    sc_out = 1.0f;
  }

  float x1 = bf2f(ptr[d]);
  float x2 = bf2f(ptr[d + 64]);
  ptr[d] = f2bf((x1 * cs - x2 * sn) * sc_out);
  ptr[d + 64] = f2bf((x2 * cs + x1 * sn) * sc_out);
}

// ---------------------------------------------------------------------------
// V transpose: Vb [S,1024] bf16 -> Vt [1024,S] bf16 (per-dim rows, key contig)
// ---------------------------------------------------------------------------
__global__ __launch_bounds__(256) void transp_v(
    const unsigned short* __restrict__ Vb, unsigned short* __restrict__ Vt) {
  __shared__ unsigned short t[64][72];
  const int s0 = blockIdx.x * 64;
  const int c0 = blockIdx.y * 64;
  const int tid = threadIdx.x;
#pragma unroll
  for (int i = 0; i < 2; i++) {
    int c = tid + i * 256;
    int r = c >> 3, ch = c & 7;
    *(short8*)&t[r][ch * 8] = *(const short8*)&Vb[(size_t)(s0 + r) * 1024 + c0 + ch * 8];
  }
  __syncthreads();
#pragma unroll
  for (int i = 0; i < 4; i++) {
    int c = tid + i * 256;
    int orow = c >> 4, oc4 = (c & 15) * 4;
    ushort4 o;
    o.x = t[oc4 + 0][orow]; o.y = t[oc4 + 1][orow];
    o.z = t[oc4 + 2][orow]; o.w = t[oc4 + 3][orow];
    *(ushort4*)&Vt[(size_t)(c0 + orow) * S_LEN + s0 + oc4] = o;
  }
}

// ---------------------------------------------------------------------------
// MFMA flash attention v3: 16-query strips, 4096 waves, balanced assignment.
// Wave = one 16-query strip of one head; 4 waves/block with complementary
// strip pairing {2p, 127-2p, 2p+1, 126-2p} so block durations are uniform;
// p scrambled so co-resident blocks span different duration quartiles.
// Barrier-free K-loop: S^T = mfma(K,Q) (query = lane&15 -> 2-shuffle softmax,
// per-lane alpha rescale), P via wave-private LDS, O^T = mfma(Vt, P).
// __launch_bounds__(256,4): VGPR<=128 -> 4 blocks/CU = 16 waves/CU.
// ---------------------------------------------------------------------------
#define AK 64
#define PSTR 72  // shorts; 36 dwords/row

__global__ __launch_bounds__(256, 4) void attn_mfma(
    const unsigned short* __restrict__ Qb, const unsigned short* __restrict__ Kb,
    const unsigned short* __restrict__ Vt, unsigned short* __restrict__ Ob) {
  const int b = blockIdx.x;
  const int h = b >> 5;                 // 32 blocks per head
  const int p = (b + 9 * h) & 31;       // scrambled pair-group
  const int kvh = h >> 2;

  const int tid = threadIdx.x;
  const int w = tid >> 6;
  const int lane = tid & 63;
  const int lrow = lane & 15;   // query col (S^T/O^T) / key row (K) / dim row (Vt)
  const int lk8 = lane >> 4;    // k-chunk / key-quad

  // strip id within head: complementary pairs for per-block balance
  int t;
  if (w == 0)      t = 2 * p;
  else if (w == 1) t = 127 - 2 * p;
  else if (w == 2) t = 2 * p + 1;
  else             t = 126 - 2 * p;
  const int wqb = t * 16;  // wave's first query

  __shared__ unsigned short Ps[4 * 16 * PSTR];  // 9216 B, wave-private slices
  unsigned short* Pw = &Ps[w * 16 * PSTR];

  // Q fragments (B-operand: lane&15 = query, k = dims), direct from global.
  short8 qf[4];
#pragma unroll
  for (int ks = 0; ks < 4; ks++)
    qf[ks] = *(const short8*)&Qb[(size_t)(wqb + lrow) * 4096 +
                                 h * 128 + ks * 32 + lk8 * 8];

  f32x4 acc[8];  // O^T: [dim-tile]
  float m_i = -1e30f, l_i = 0.f;
#pragma unroll
  for (int n = 0; n < 8; n++) acc[n] = (f32x4){0.f, 0.f, 0.f, 0.f};

  const int nkt = (t >> 2) + 1;  // causal: keys <= 16t+16, tiles of 64

  for (int kt = 0; kt < nkt; kt++) {
    const int kb = kt * AK;

    // ---- S^T = K Q^T : a=K rows (key), b=Q rows (query) ----
    f32x4 s[4];  // [key-tile n]
#pragma unroll
    for (int n = 0; n < 4; n++) s[n] = (f32x4){0.f, 0.f, 0.f, 0.f};

#pragma unroll
    for (int ks = 0; ks < 4; ks++) {
      short8 kf[4];
#pragma unroll
      for (int n = 0; n < 4; n++)
        kf[n] = *(const short8*)&Kb[(size_t)(kb + n * 16 + lrow) * 1024 +
                                    kvh * 128 + ks * 32 + lk8 * 8];
#pragma unroll
      for (int n = 0; n < 4; n++)
        s[n] = __builtin_amdgcn_mfma_f32_16x16x32_bf16(kf[n], qf[ks], s[n], 0, 0, 0);
    }

    // ---- Causal mask: rows=keys (lk8*4+r), cols=queries (lrow) ----
    if (kb + AK - 1 > wqb) {
      int query = wqb + lrow;
#pragma unroll
      for (int n = 0; n < 4; n++) {
        int keyb = kb + n * 16 + lk8 * 4;
#pragma unroll
        for (int r = 0; r < 4; r++)
          if (keyb + r > query) s[n][r] = -1e30f;
      }
    }

    // ---- Online softmax: 16 in-lane scores per query + 2 shuffles ----
    {
      float mx = -1e30f;
#pragma unroll
      for (int n = 0; n < 4; n++)
#pragma unroll
        for (int r = 0; r < 4; r++) mx = fmaxf(mx, s[n][r]);
      mx = fmaxf(mx, __shfl_xor(mx, 16, 64));
      mx = fmaxf(mx, __shfl_xor(mx, 32, 64));
      float mn = fmaxf(m_i, mx);
      float al = exp2f(m_i - mn);
      m_i = mn;
      float ls = 0.f;
#pragma unroll
      for (int n = 0; n < 4; n++)
#pragma unroll
        for (int r = 0; r < 4; r++) {
          float e = exp2f(s[n][r] - mn);
          s[n][r] = e;
          ls += e;
        }
      ls += __shfl_xor(ls, 16, 64);
      ls += __shfl_xor(ls, 32, 64);
      l_i = l_i * al + ls;
#pragma unroll
      for (int n = 0; n < 8; n++)
#pragma unroll
        for (int r = 0; r < 4; r++) acc[n][r] *= al;
    }

    // ---- P -> wave-private LDS [query][key] ----
#pragma unroll
    for (int n = 0; n < 4; n++) {
      ushort4 pk;
      pk.x = f2bf(s[n][0]); pk.y = f2bf(s[n][1]);
      pk.z = f2bf(s[n][2]); pk.w = f2bf(s[n][3]);
      *(ushort4*)&Pw[lrow * PSTR + n * 16 + lk8 * 4] = pk;
    }

    // ---- O^T += V^T P^T : a=Vt rows (dim), b=P rows (query) ----
#pragma unroll
    for (int ks2 = 0; ks2 < 2; ks2++) {
      short8 pf = *(const short8*)&Pw[lrow * PSTR + ks2 * 32 + lk8 * 8];
#pragma unroll
      for (int n = 0; n < 8; n++) {
        short8 vf = *(const short8*)&Vt[(size_t)(kvh * 128 + n * 16 + lrow) * S_LEN +
                                        kb + ks2 * 32 + lk8 * 8];
        acc[n] = __builtin_amdgcn_mfma_f32_16x16x32_bf16(vf, pf, acc[n], 0, 0, 0);
      }
    }
  }

  // ---- Epilogue: normalize, store O (4 consecutive dims per lane = 8B) ----
  {
    float inv = 1.0f / l_i;
    int row = wqb + lrow;
#pragma unroll
    for (int n = 0; n < 8; n++) {
      ushort4 o;
      o.x = f2bf(acc[n][0] * inv); o.y = f2bf(acc[n][1] * inv);
      o.z = f2bf(acc[n][2] * inv); o.w = f2bf(acc[n][3] * inv);
      *(ushort4*)&Ob[(size_t)row * 4096 + h * 128 + n * 16 + lk8 * 4] = o;
    }
  }
}

// ---------------------------------------------------------------------------
extern "C" void kernel_launch(void* const* d_in, const int* in_sizes, int n_in,
                              void* d_out, int out_size, void* d_ws, size_t ws_size,
                              hipStream_t stream) {
  const float* X  = (const float*)d_in[0];
  const float* Wq = (const float*)d_in[1];
  const float* Wk = (const float*)d_in[2];
  const float* Wv = (const float*)d_in[3];
  const float* Wo = (const float*)d_in[4];
  float* out = (float*)d_out;

  char* p = (char*)d_ws;
  unsigned short* Qb  = (unsigned short*)p; p += (size_t)S_LEN * 4096 * 2;
  unsigned short* Kb  = (unsigned short*)p; p += (size_t)S_LEN * 1024 * 2;
  unsigned short* Vb  = (unsigned short*)p; p += (size_t)S_LEN * 1024 * 2;
  unsigned short* Vt  = (unsigned short*)p; p += (size_t)1024 * S_LEN * 2;
  unsigned short* Xb  = (unsigned short*)p; p += (size_t)S_LEN * 4096 * 2;
  unsigned short* Wqb = (unsigned short*)p; p += (size_t)4096 * 4096 * 2;
  unsigned short* Wkb = (unsigned short*)p; p += (size_t)1024 * 4096 * 2;
  unsigned short* Wvb = (unsigned short*)p; p += (size_t)1024 * 4096 * 2;
  unsigned short* Ob  = Xb;   // Xb dead after gemm_qkv
  unsigned short* Wob = Wqb;  // Wqb dead after gemm_qkv

  // 1. fp32 -> bf16
  conv_bf16<<<(S_LEN * 4096 / 4 + 255) / 256, 256, 0, stream>>>(X, Xb, S_LEN * 4096);
  conv_bf16<<<(4096 * 4096 / 4 + 255) / 256, 256, 0, stream>>>(Wq, Wqb, 4096 * 4096);
  conv_bf16<<<(1024 * 4096 / 4 + 255) / 256, 256, 0, stream>>>(Wk, Wkb, 1024 * 4096);
  conv_bf16<<<(1024 * 4096 / 4 + 255) / 256, 256, 0, stream>>>(Wv, Wvb, 1024 * 4096);

  // 2. Fused QKV projection -> bf16
  gemm_qkv<<<dim3(6144 / 128, S_LEN / 128), 256, 0, stream>>>(Xb, Wqb, Wkb, Wvb, Qb, Kb, Vb);

  // 3. RoPE in-place (Q pre-scaled into exp2 domain)
  int rope_threads = S_LEN * (N_HEADS + N_KV) * 64;
  rope_kernel<<<rope_threads / 256, 256, 0, stream>>>(Qb, Kb);

  // 4. V transpose for MFMA A-operand layout
  transp_v<<<dim3(S_LEN / 64, 1024 / 64), 256, 0, stream>>>(Vb, Vt);

  // 5. Convert Wo (into Wqb space)
  conv_bf16<<<(4096 * 4096 / 4 + 255) / 256, 256, 0, stream>>>(Wo, Wob, 4096 * 4096);

  // 6. MFMA flash attention v3 -> bf16 (into Xb space); 1024 balanced blocks
  attn_mfma<<<32 * N_HEADS, 256, 0, stream>>>(Qb, Kb, Vt, Ob);

  // 7. Output projection
  gemm_out<<<dim3(4096 / 128, S_LEN / 128), 256, 0, stream>>>(Ob, Wob, out);
}

// Round 7
// 577.125 us; speedup vs baseline: 1.2615x; 1.2615x over previous
//
#include <hip/hip_runtime.h>
#include <hip/hip_bf16.h>
#include <math.h>

// Problem constants
#define S_LEN 2048
#define HIDDEN 4096
#define N_HEADS 32
#define N_KV 8
#define HEAD_DIM 128

typedef __attribute__((ext_vector_type(8))) short short8;   // 8 bf16 = 4 VGPRs
typedef __attribute__((ext_vector_type(4))) float f32x4;    // MFMA C/D frag

typedef __attribute__((address_space(3))) unsigned int as3_u32;
typedef const __attribute__((address_space(1))) unsigned int as1_u32;

__device__ __forceinline__ void gload16(const void* g, void* lds) {
  __builtin_amdgcn_global_load_lds((as1_u32*)g, (as3_u32*)lds, 16, 0, 0);
}

__device__ __forceinline__ unsigned short f2bf(float f) {
  unsigned int u = __float_as_uint(f);
  return (unsigned short)((u + 0x7fff + ((u >> 16) & 1)) >> 16);  // RNE
}
__device__ __forceinline__ float bf2f(unsigned short u) {
  return __uint_as_float(((unsigned int)u) << 16);
}

// ---------------------------------------------------------------------------
// fp32 -> bf16 conversion, 4 elems/thread
// ---------------------------------------------------------------------------
__global__ void conv_bf16(const float* __restrict__ in, unsigned short* __restrict__ out, int n) {
  int i = (blockIdx.x * blockDim.x + threadIdx.x) * 4;
  if (i >= n) return;
  float4 v = *(const float4*)&in[i];
  ushort4 o;
  o.x = f2bf(v.x); o.y = f2bf(v.y); o.z = f2bf(v.z); o.w = f2bf(v.w);
  *(ushort4*)&out[i] = o;
}

// ---------------------------------------------------------------------------
// m97-style bf16 MFMA GEMM core: one 128x128 C-tile per 256-thread block.
// ---------------------------------------------------------------------------
__device__ __forceinline__ void storeC(float* C, float v) { *C = v; }
__device__ __forceinline__ void storeC(unsigned short* C, float v) { *C = f2bf(v); }

template <typename OutT>
__device__ __forceinline__ void gemm_core_128(
    const unsigned short* __restrict__ A, const unsigned short* __restrict__ B,
    OutT* __restrict__ C, int K, int ldc) {
  __shared__ unsigned short As[128 * 32];
  __shared__ unsigned short Bs[128 * 32];

  const int tid = threadIdx.x;
  const int w = tid >> 6;
  const int lane = tid & 63;
  const int wr = (w >> 1) * 64;
  const int wc = (w & 1) * 64;
  const int lrow = lane & 15;
  const int lk8 = lane >> 4;

  f32x4 acc[4][4];
#pragma unroll
  for (int i = 0; i < 4; i++)
#pragma unroll
    for (int j = 0; j < 4; j++) acc[i][j] = (f32x4){0.f, 0.f, 0.f, 0.f};

  const int sr = (lane >> 2);
  const int sc = (lane & 3) * 8;

  for (int k0 = 0; k0 < K; k0 += 32) {
    __syncthreads();
#pragma unroll
    for (int s = 0; s < 2; s++) {
      int r = w * 32 + s * 16 + sr;
      gload16(&A[(size_t)r * K + k0 + sc], &As[(w * 32 + s * 16) * 32]);
      gload16(&B[(size_t)r * K + k0 + sc], &Bs[(w * 32 + s * 16) * 32]);
    }
    __syncthreads();

    short8 a[4], b[4];
#pragma unroll
    for (int i = 0; i < 4; i++)
      a[i] = *(const short8*)&As[(wr + i * 16 + lrow) * 32 + lk8 * 8];
#pragma unroll
    for (int j = 0; j < 4; j++)
      b[j] = *(const short8*)&Bs[(wc + j * 16 + lrow) * 32 + lk8 * 8];
#pragma unroll
    for (int i = 0; i < 4; i++)
#pragma unroll
      for (int j = 0; j < 4; j++)
        acc[i][j] = __builtin_amdgcn_mfma_f32_16x16x32_bf16(a[i], b[j], acc[i][j], 0, 0, 0);
  }

#pragma unroll
  for (int i = 0; i < 4; i++)
#pragma unroll
    for (int j = 0; j < 4; j++) {
      int col = wc + j * 16 + lrow;
#pragma unroll
      for (int r = 0; r < 4; r++) {
        int row = wr + i * 16 + lk8 * 4 + r;
        storeC(&C[(size_t)row * ldc + col], acc[i][j][r]);
      }
    }
}

// Fused QKV projection -> bf16 outputs Qb [S,4096], Kb [S,1024], Vb [S,1024]
__global__ __launch_bounds__(256) void gemm_qkv(
    const unsigned short* __restrict__ Xb,
    const unsigned short* __restrict__ Wqb, const unsigned short* __restrict__ Wkb,
    const unsigned short* __restrict__ Wvb,
    unsigned short* __restrict__ Qb, unsigned short* __restrict__ Kb,
    unsigned short* __restrict__ Vb) {
  const int colBase = blockIdx.x * 128;
  const int rowBase = blockIdx.y * 128;
  const unsigned short* B;
  unsigned short* C;
  int ldc, ccol;
  if (colBase < 4096)      { B = Wqb + (size_t)colBase * HIDDEN;          C = Qb; ldc = 4096; ccol = colBase; }
  else if (colBase < 5120) { B = Wkb + (size_t)(colBase - 4096) * HIDDEN; C = Kb; ldc = 1024; ccol = colBase - 4096; }
  else                     { B = Wvb + (size_t)(colBase - 5120) * HIDDEN; C = Vb; ldc = 1024; ccol = colBase - 5120; }
  gemm_core_128(Xb + (size_t)rowBase * HIDDEN, B,
                C + (size_t)rowBase * ldc + ccol, HIDDEN, ldc);
}

// Output projection: [2048,4096](bf16) @ Wo^T -> fp32 out
__global__ __launch_bounds__(256) void gemm_out(
    const unsigned short* __restrict__ Ob, const unsigned short* __restrict__ Wob,
    float* __restrict__ C) {
  const int colBase = blockIdx.x * 128;
  const int rowBase = blockIdx.y * 128;
  gemm_core_128(Ob + (size_t)rowBase * HIDDEN, Wob + (size_t)colBase * HIDDEN,
                C + (size_t)rowBase * HIDDEN + colBase, HIDDEN, HIDDEN);
}

// ---------------------------------------------------------------------------
// RoPE on bf16 Q/K, writing PACKED tile layouts:
//   Qp: per (head, 16-query strip) contiguous 4 KB:
//       Qp[((h*128 + (s>>4))*16 + (s&15))*128 + d]
//   Kp: per (kv head, 64-key tile) contiguous 16 KB:
//       Kp[((kvh*32 + (s>>6))*64 + (s&63))*128 + d]
// Q additionally scaled by 1/sqrt(128) * log2(e)  (exp2-domain softmax).
// ---------------------------------------------------------------------------
#define QSCALE 0.12753102123752056f  // 0.08838834764831845 * 1.4426950408889634

__global__ void rope_kernel(const unsigned short* __restrict__ Q,
                            const unsigned short* __restrict__ K,
                            unsigned short* __restrict__ Qp,
                            unsigned short* __restrict__ Kp) {
  int idx = blockIdx.x * blockDim.x + threadIdx.x;
  int d = idx & 63;
  int sh = idx >> 6;
  int h = sh % (N_HEADS + N_KV);
  int s = sh / (N_HEADS + N_KV);
  if (s >= S_LEN) return;

  float freq = expf(-(float)d * (9.210340371976184f / 64.0f));
  float ang = (float)s * freq;
  float sn, cs;
  sincosf(ang, &sn, &cs);

  const unsigned short* src;
  unsigned short* dst;
  float sc_out;
  if (h < N_HEADS) {
    src = Q + ((size_t)s * N_HEADS + h) * HEAD_DIM;
    dst = Qp + (((size_t)h * 128 + (s >> 4)) * 16 + (s & 15)) * HEAD_DIM;
    sc_out = QSCALE;
  } else {
    int kvh = h - N_HEADS;
    src = K + ((size_t)s * N_KV + kvh) * HEAD_DIM;
    dst = Kp + (((size_t)kvh * 32 + (s >> 6)) * 64 + (s & 63)) * HEAD_DIM;
    sc_out = 1.0f;
  }

  float x1 = bf2f(src[d]);
  float x2 = bf2f(src[d + 64]);
  dst[d] = f2bf((x1 * cs - x2 * sn) * sc_out);
  dst[d + 64] = f2bf((x2 * cs + x1 * sn) * sc_out);
}

// ---------------------------------------------------------------------------
// V transpose into PACKED tiles: Vb [S,1024] -> Vp, per (kvh, 64-key tile)
// contiguous 16 KB of [128 dims][64 keys]:
//   Vp[((kvh*32 + kt)*128 + d)*64 + k]
// ---------------------------------------------------------------------------
__global__ __launch_bounds__(256) void transp_v(
    const unsigned short* __restrict__ Vb, unsigned short* __restrict__ Vp) {
  __shared__ unsigned short t[64][72];
  const int s0 = blockIdx.x * 64;   // key tile base
  const int c0 = blockIdx.y * 64;   // flat dim base (kvh*128 + d)
  const int kt = s0 >> 6;
  const int tid = threadIdx.x;
#pragma unroll
  for (int i = 0; i < 2; i++) {
    int c = tid + i * 256;
    int r = c >> 3, ch = c & 7;
    *(short8*)&t[r][ch * 8] = *(const short8*)&Vb[(size_t)(s0 + r) * 1024 + c0 + ch * 8];
  }
  __syncthreads();
#pragma unroll
  for (int i = 0; i < 4; i++) {
    int c = tid + i * 256;
    int orow = c >> 4, oc4 = (c & 15) * 4;
    int g = c0 + orow;               // flat dim
    int kvh = g >> 7, d = g & 127;
    ushort4 o;
    o.x = t[oc4 + 0][orow]; o.y = t[oc4 + 1][orow];
    o.z = t[oc4 + 2][orow]; o.w = t[oc4 + 3][orow];
    *(ushort4*)&Vp[(((size_t)kvh * 32 + kt) * 128 + d) * 64 + oc4] = o;
  }
}

// ---------------------------------------------------------------------------
// MFMA flash attention v4: gemm-style staging from PACKED contiguous tiles.
// Block = 128 queries x 1 head, 4 waves x 32 queries. K-tiles of 64.
// K (64x128) and V^T (128x64) staged per tile via global_load_lds width=16
// from fully contiguous 16 KB buffers, with a 16B-granular XOR swizzle baked
// into the per-lane SOURCE address so LDS fragment reads are conflict-free
// (LDS dest must stay lane-contiguous -> cannot pad).
//   K LDS:  chunk (row r, pos p) holds global chunk (r, p ^ (r&15))
//   Vt LDS: chunk (row r, pos p) holds global chunk (r, p ^ (r&7))
// Transposed-S softmax (query = lane&15): 2 shuffles per strip, per-lane
// alpha rescale. Grid 512: blocks b and b+256 have complementary qi.
// LDS 50 KB -> 3 blocks/CU.
// ---------------------------------------------------------------------------
#define AK 64
#define PSTR 72

__global__ __launch_bounds__(256, 3) void attn_mfma(
    const unsigned short* __restrict__ Qp, const unsigned short* __restrict__ Kp,
    const unsigned short* __restrict__ Vp, unsigned short* __restrict__ Ob) {
  const int b = blockIdx.x;
  const int h = b & 31;
  const int qi = (b < 256) ? (b >> 5) : (15 - ((b - 256) >> 5));
  const int kvh = h >> 2;

  const int tid = threadIdx.x;
  const int w = tid >> 6;
  const int lane = tid & 63;
  const int lrow = lane & 15;
  const int lk8 = lane >> 4;

  __shared__ unsigned short Ks[64 * 128];      // 16 KB, swizzled
  __shared__ unsigned short Vts[128 * 64];     // 16 KB, swizzled
  __shared__ unsigned short Ps[4 * 32 * PSTR]; // 18 KB, wave-private
  unsigned short* Pw = &Ps[w * 32 * PSTR];

  // ---- Q fragments from packed strips (4 KB contiguous each) ----
  short8 qf[2][4];
  const int t0 = qi * 8 + w * 2;
#pragma unroll
  for (int i = 0; i < 2; i++)
#pragma unroll
    for (int ks = 0; ks < 4; ks++)
      qf[i][ks] = *(const short8*)&Qp[(((size_t)h * 128 + t0 + i) * 16 + lrow) * 128 +
                                      ks * 32 + lk8 * 8];

  f32x4 acc[8][2];  // O^T: [dim-tile][query-strip]
  float m_i[2], l_i[2];
#pragma unroll
  for (int n = 0; n < 8; n++)
#pragma unroll
    for (int i = 0; i < 2; i++) acc[n][i] = (f32x4){0.f, 0.f, 0.f, 0.f};
  m_i[0] = m_i[1] = -1e30f;
  l_i[0] = l_i[1] = 0.f;

  const int nkt = 2 * qi + 2;

  for (int kt = 0; kt < nkt; kt++) {
    const int kb = kt * AK;
    const unsigned short* Kt  = Kp + ((size_t)kvh * 32 + kt) * 8192;
    const unsigned short* Vtt = Vp + ((size_t)kvh * 32 + kt) * 8192;

    __syncthreads();  // all waves done reading previous tile
    // ---- Stage K + V^T (16 KB each) with swizzled contiguous sources ----
#pragma unroll
    for (int j = 0; j < 4; j++) {
      int seg = w * 4 + j;                  // 0..15, 1 KB LDS segment
      // K: lds slot (r = seg*4 + lk8, p = lrow) <- global chunk (r, p^(r&15))
      int kr = seg * 4 + lk8;
      int kc = lrow ^ (kr & 15);
      gload16(Kt + ((size_t)kr * 16 + kc) * 8, &Ks[seg * 512]);
      // Vt: lds slot (r = seg*8 + lane>>3, p = lane&7) <- chunk (r, p^(r&7))
      int vr = seg * 8 + (lane >> 3);
      int vc = (lane & 7) ^ (vr & 7);
      gload16(Vtt + ((size_t)vr * 8 + vc) * 8, &Vts[seg * 512]);
    }
    __syncthreads();  // barrier drains vmcnt -> staged data visible

    // ---- S^T = K Q^T ----
    f32x4 s[2][4];
#pragma unroll
    for (int i = 0; i < 2; i++)
#pragma unroll
      for (int n = 0; n < 4; n++) s[i][n] = (f32x4){0.f, 0.f, 0.f, 0.f};

#pragma unroll
    for (int ks = 0; ks < 4; ks++) {
      short8 kf[4];
#pragma unroll
      for (int n = 0; n < 4; n++)
        kf[n] = *(const short8*)&Ks[(n * 16 + lrow) * 128 + (((ks * 4 + lk8) ^ lrow)) * 8];
#pragma unroll
      for (int i = 0; i < 2; i++)
#pragma unroll
        for (int n = 0; n < 4; n++)
          s[i][n] = __builtin_amdgcn_mfma_f32_16x16x32_bf16(kf[n], qf[i][ks], s[i][n], 0, 0, 0);
    }

    // ---- Causal mask: rows=keys (lk8*4+r), cols=queries (lrow) ----
    const int wqb = qi * 128 + w * 32;
    if (kb + AK - 1 > wqb) {
#pragma unroll
      for (int i = 0; i < 2; i++) {
        int query = wqb + i * 16 + lrow;
#pragma unroll
        for (int n = 0; n < 4; n++) {
          int keyb = kb + n * 16 + lk8 * 4;
#pragma unroll
          for (int r = 0; r < 4; r++)
            if (keyb + r > query) s[i][n][r] = -1e30f;
        }
      }
    }

    // ---- Online softmax (exp2): 16 in-lane scores + 2 shuffles per strip ----
#pragma unroll
    for (int i = 0; i < 2; i++) {
      float mx = -1e30f;
#pragma unroll
      for (int n = 0; n < 4; n++)
#pragma unroll
        for (int r = 0; r < 4; r++) mx = fmaxf(mx, s[i][n][r]);
      mx = fmaxf(mx, __shfl_xor(mx, 16, 64));
      mx = fmaxf(mx, __shfl_xor(mx, 32, 64));
      float mn = fmaxf(m_i[i], mx);
      float al = exp2f(m_i[i] - mn);
      m_i[i] = mn;
      float ls = 0.f;
#pragma unroll
      for (int n = 0; n < 4; n++)
#pragma unroll
        for (int r = 0; r < 4; r++) {
          float e = exp2f(s[i][n][r] - mn);
          s[i][n][r] = e;
          ls += e;
        }
      ls += __shfl_xor(ls, 16, 64);
      ls += __shfl_xor(ls, 32, 64);
      l_i[i] = l_i[i] * al + ls;
#pragma unroll
      for (int n = 0; n < 8; n++)
#pragma unroll
        for (int r = 0; r < 4; r++) acc[n][i][r] *= al;
    }

    // ---- P -> wave-private LDS [query][key] ----
#pragma unroll
    for (int i = 0; i < 2; i++)
#pragma unroll
      for (int n = 0; n < 4; n++) {
        ushort4 pk;
        pk.x = f2bf(s[i][n][0]); pk.y = f2bf(s[i][n][1]);
        pk.z = f2bf(s[i][n][2]); pk.w = f2bf(s[i][n][3]);
        *(ushort4*)&Pw[(i * 16 + lrow) * PSTR + n * 16 + lk8 * 4] = pk;
      }

    // ---- O^T += V^T P^T ----
#pragma unroll
    for (int ks2 = 0; ks2 < 2; ks2++) {
      short8 pf[2];
#pragma unroll
      for (int i = 0; i < 2; i++)
        pf[i] = *(const short8*)&Pw[(i * 16 + lrow) * PSTR + ks2 * 32 + lk8 * 8];
#pragma unroll
      for (int n = 0; n < 8; n++) {
        short8 vf = *(const short8*)&Vts[(n * 16 + lrow) * 64 +
                                         (((ks2 * 4 + lk8) ^ (lrow & 7))) * 8];
#pragma unroll
        for (int i = 0; i < 2; i++)
          acc[n][i] = __builtin_amdgcn_mfma_f32_16x16x32_bf16(vf, pf[i], acc[n][i], 0, 0, 0);
      }
    }
  }

  // ---- Epilogue: normalize, store O [s][h*128+d] ----
#pragma unroll
  for (int i = 0; i < 2; i++) {
    float inv = 1.0f / l_i[i];
    int row = qi * 128 + w * 32 + i * 16 + lrow;
#pragma unroll
    for (int n = 0; n < 8; n++) {
      ushort4 o;
      o.x = f2bf(acc[n][i][0] * inv); o.y = f2bf(acc[n][i][1] * inv);
      o.z = f2bf(acc[n][i][2] * inv); o.w = f2bf(acc[n][i][3] * inv);
      *(ushort4*)&Ob[(size_t)row * 4096 + h * 128 + n * 16 + lk8 * 4] = o;
    }
  }
}

// ---------------------------------------------------------------------------
extern "C" void kernel_launch(void* const* d_in, const int* in_sizes, int n_in,
                              void* d_out, int out_size, void* d_ws, size_t ws_size,
                              hipStream_t stream) {
  const float* X  = (const float*)d_in[0];
  const float* Wq = (const float*)d_in[1];
  const float* Wk = (const float*)d_in[2];
  const float* Wv = (const float*)d_in[3];
  const float* Wo = (const float*)d_in[4];
  float* out = (float*)d_out;

  char* p = (char*)d_ws;
  unsigned short* Qb  = (unsigned short*)p; p += (size_t)S_LEN * 4096 * 2;  // 16.8 MB
  unsigned short* Kb  = (unsigned short*)p; p += (size_t)S_LEN * 1024 * 2;  //  4.2 MB
  unsigned short* Vb  = (unsigned short*)p; p += (size_t)S_LEN * 1024 * 2;  //  4.2 MB
  unsigned short* Qp  = (unsigned short*)p; p += (size_t)S_LEN * 4096 * 2;  // 16.8 MB
  unsigned short* Kp  = (unsigned short*)p; p += (size_t)S_LEN * 1024 * 2;  //  4.2 MB
  unsigned short* Vp  = (unsigned short*)p; p += (size_t)S_LEN * 1024 * 2;  //  4.2 MB
  unsigned short* Xb  = (unsigned short*)p; p += (size_t)S_LEN * 4096 * 2;  // 16.8 MB
  unsigned short* Wqb = (unsigned short*)p; p += (size_t)4096 * 4096 * 2;   // 33.6 MB
  unsigned short* Wkb = (unsigned short*)p; p += (size_t)1024 * 4096 * 2;   //  8.4 MB
  unsigned short* Wvb = (unsigned short*)p; p += (size_t)1024 * 4096 * 2;   //  8.4 MB
  unsigned short* Ob  = Xb;   // Xb dead after gemm_qkv
  unsigned short* Wob = Wqb;  // Wqb dead after gemm_qkv

  // 1. fp32 -> bf16
  conv_bf16<<<(S_LEN * 4096 / 4 + 255) / 256, 256, 0, stream>>>(X, Xb, S_LEN * 4096);
  conv_bf16<<<(4096 * 4096 / 4 + 255) / 256, 256, 0, stream>>>(Wq, Wqb, 4096 * 4096);
  conv_bf16<<<(1024 * 4096 / 4 + 255) / 256, 256, 0, stream>>>(Wk, Wkb, 1024 * 4096);
  conv_bf16<<<(1024 * 4096 / 4 + 255) / 256, 256, 0, stream>>>(Wv, Wvb, 1024 * 4096);

  // 2. Fused QKV projection -> bf16
  gemm_qkv<<<dim3(6144 / 128, S_LEN / 128), 256, 0, stream>>>(Xb, Wqb, Wkb, Wvb, Qb, Kb, Vb);

  // 3. RoPE -> packed Qp/Kp tile layouts (Q pre-scaled into exp2 domain)
  int rope_threads = S_LEN * (N_HEADS + N_KV) * 64;
  rope_kernel<<<rope_threads / 256, 256, 0, stream>>>(Qb, Kb, Qp, Kp);

  // 4. V transpose -> packed Vp tiles
  transp_v<<<dim3(S_LEN / 64, 1024 / 64), 256, 0, stream>>>(Vb, Vp);

  // 5. Convert Wo (into Wqb space)
  conv_bf16<<<(4096 * 4096 / 4 + 255) / 256, 256, 0, stream>>>(Wo, Wob, 4096 * 4096);

  // 6. MFMA flash attention v4 -> bf16 (into Xb space)
  attn_mfma<<<512, 256, 0, stream>>>(Qp, Kp, Vp, Ob);

  // 7. Output projection
  gemm_out<<<dim3(4096 / 128, S_LEN / 128), 256, 0, stream>>>(Ob, Wob, out);
}